// Round 6
// baseline (246.055 us; speedup 1.0000x reference)
//
#include <hip/hip_runtime.h>

#pragma clang fp contract(off)

#define B_   512
#define N_   16384
#define A_   64
#define TPB  1024
#define CAP  2048

// Wave-aggregated LDS histogram add: dedup equal buckets via ballot so the
// DS unit sees ONE atomic per distinct bucket per wave instead of a ~8-16-way
// same-address serialized RMW (the distances span ~2 float exponents, so the
// 11-bit histogram has ~8 hot buckets -> worst-case within-wave contention).
__device__ __forceinline__ void hist_add_wave(unsigned* hist, unsigned bucket) {
    const int lane = threadIdx.x & 63;
    unsigned long long rem = ~0ull;               // all 64 lanes have an elem
    while (rem) {                                 // wave-uniform loop
        const int leader = __ffsll((long long)rem) - 1;
        const unsigned vb = (unsigned)__shfl((int)bucket, leader, 64);
        const unsigned long long same = __ballot(bucket == vb);
        if (lane == leader) atomicAdd(&hist[vb], (unsigned)__popcll(same));
        rem &= ~same;
    }
}

// Predicated variant (only lanes with pred contribute).
__device__ __forceinline__ void hist_add_wave_pred(unsigned* hist,
                                                   unsigned bucket, bool pred) {
    const int lane = threadIdx.x & 63;
    unsigned long long rem = __ballot(pred);
    while (rem) {                                 // wave-uniform loop
        const int leader = __ffsll((long long)rem) - 1;
        const unsigned vb = (unsigned)__shfl((int)bucket, leader, 64);
        const unsigned long long same = __ballot(pred && (bucket == vb));
        if (lane == leader) atomicAdd(&hist[vb], (unsigned)__popcll(same));
        rem &= ~same;
    }
}

// One block per batch: centroid (bit-exact numpy order) + distances +
// exact top-k select (16-bit radix + boundary rank) + both mask writes.
// Round-0 structure (direct float4 loads, register-resident bits/mask);
// LDS staging removed (rounds 2-5 proved it null). The one change vs the
// 78us plateau family: all LDS atomics are wave-aggregated.
__global__ __launch_bounds__(TPB) void fused_kernel(
    const float* __restrict__ pos,   const float* __restrict__ mask,
    const float* __restrict__ apos,  const float* __restrict__ amask,
    const int*   __restrict__ topk_ptr,
    float* __restrict__ out0, float* __restrict__ out1)
{
#pragma clang fp contract(off)
    __shared__ unsigned       hist[2048];     // 8 KB: 11-bit histogram
    __shared__ unsigned       hist2[32];      // 5-bit refinement
    __shared__ unsigned       cand_bits[CAP]; // boundary candidates
    __shared__ unsigned short cand_idx[CAP];
    __shared__ unsigned char  sel_flags[CAP]; // rank<j per candidate
    __shared__ float          s_atoms[A_ * 3 + A_];  // 192 pos + 64 mask
    __shared__ unsigned s_B11, s_less11, s_P16, s_j, s_ncand, s_k;

    const int tid = threadIdx.x;
    const int l   = tid & 63;
    const int b   = blockIdx.x;
    const float* __restrict__ p = pos  + (size_t)b * N_ * 3;
    const float* __restrict__ m = mask + (size_t)b * N_;

    // ---- init: zero hists, stage atoms coalesced, load k ------------------
    hist[tid]        = 0u;
    hist[tid + 1024] = 0u;
    if (tid < 32) hist2[tid] = 0u;
    if (tid < 256)
        s_atoms[tid] = (tid < 192) ? apos[(size_t)b * 192 + tid]
                                   : amask[(size_t)b * 64 + (tid - 192)];
    if (tid == 0) {
        s_ncand = 0u;
        int kk = *topk_ptr;
        if (kk < 0)  kk = 0;
        if (kk > N_) kk = N_;
        s_k = (unsigned)kk;
    }
    __syncthreads();

    // ---- centroid, per-wave (identical arithmetic -> bit-exact, no extra
    //      barrier): lanes 0..2 comp sums (numpy sequential), lane 3 mask ---
    float cx, cy, cz;
    {
        float comp = 0.0f, ms = 0.0f;
        if (l < 3) {
            comp = s_atoms[l];
            for (int a = 1; a < A_; ++a) comp += s_atoms[a * 3 + l];
        }
        if (l == 3) {
            const float* am = s_atoms + 192;
            float r0 = am[0], r1 = am[1], r2 = am[2], r3 = am[3];
            float r4 = am[4], r5 = am[5], r6 = am[6], r7 = am[7];
            for (int i = 8; i < A_; i += 8) {
                r0 += am[i + 0]; r1 += am[i + 1]; r2 += am[i + 2]; r3 += am[i + 3];
                r4 += am[i + 4]; r5 += am[i + 5]; r6 += am[i + 6]; r7 += am[i + 7];
            }
            ms = ((r0 + r1) + (r2 + r3)) + ((r4 + r5) + (r6 + r7));
        }
        ms = __shfl(ms, 3, 64);
        const float cc = (l < 3) ? comp / ms : 0.0f;  // correctly-rounded div
        cx = __shfl(cc, 0, 64);
        cy = __shfl(cc, 1, 64);
        cz = __shfl(cc, 2, 64);
    }

    const unsigned k = s_k;

    // ---- Phase A: distances (bit-exact), aggregated hist ------------------
    unsigned rbits[16];
    float    rmv[16];
#pragma unroll
    for (int it = 0; it < 4; ++it) {
        const int i0 = it * 4096 + tid * 4;
        const float4 pa = *(const float4*)(p + (size_t)i0 * 3);
        const float4 pb = *(const float4*)(p + (size_t)i0 * 3 + 4);
        const float4 pc = *(const float4*)(p + (size_t)i0 * 3 + 8);
        const float4 mv = *(const float4*)(m + i0);
        const float px[4] = {pa.x, pa.w, pb.z, pc.y};
        const float py[4] = {pa.y, pb.x, pb.w, pc.z};
        const float pz[4] = {pa.z, pb.y, pc.x, pc.w};
        const float mm[4] = {mv.x, mv.y, mv.z, mv.w};
#pragma unroll
        for (int j = 0; j < 4; ++j) {
            float dx = cx - px[j], dy = cy - py[j], dz = cz - pz[j];
            float dx2 = dx * dx, dy2 = dy * dy, dz2 = dz * dz;
            float s = (dx2 + dy2) + dz2;     // numpy sum order (no FMA)
            s = s + 1e-12f;
            float d = sqrtf(s);              // correctly rounded
            d = d + (1.0f - mm[j]) * 1e10f;
            const unsigned bits = __float_as_uint(d);  // monotone, d >= 0
            rbits[it * 4 + j] = bits;
            rmv[it * 4 + j]   = mm[j];
            hist_add_wave(hist, bits >> 21);
        }
    }
    __syncthreads();

    if (k > 0) {
        // ---- Phase B: wave-0 shuffle scan finds the 11-bit bucket ---------
        if (tid < 64) {
            unsigned s = 0;
#pragma unroll
            for (int i = 0; i < 32; ++i) s += hist[tid * 32 + i];
            unsigned incl = s;
#pragma unroll
            for (int off = 1; off < 64; off <<= 1) {
                unsigned v = (unsigned)__shfl_up((int)incl, off, 64);
                if (tid >= off) incl += v;
            }
            unsigned long long bal = __ballot(incl >= k);
            const int g = __ffsll(bal) - 1;
            const unsigned cum1 = (unsigned)__shfl((int)(incl - s), g, 64);

            unsigned h2 = (tid < 32) ? hist[g * 32 + tid] : 0u;
            unsigned incl2 = h2;
#pragma unroll
            for (int off = 1; off < 64; off <<= 1) {
                unsigned v = (unsigned)__shfl_up((int)incl2, off, 64);
                if (tid >= off) incl2 += v;
            }
            unsigned long long bal2 = __ballot(tid < 32 && (cum1 + incl2 >= k));
            const int sb = __ffsll(bal2) - 1;
            const unsigned cum2 = cum1 + (unsigned)__shfl((int)(incl2 - h2), sb, 64);
            if (tid == 0) { s_B11 = (unsigned)(g * 32 + sb); s_less11 = cum2; }
        }
        __syncthreads();
        const unsigned B11 = s_B11;

        // ---- Phase C: refine low-5 bits (aggregated) ----------------------
#pragma unroll
        for (int x = 0; x < 16; ++x) {
            const unsigned v = rbits[x] >> 16;
            hist_add_wave_pred(hist2, v & 31u, (v >> 5) == B11);
        }
        __syncthreads();
        if (tid < 64) {
            unsigned h = (tid < 32) ? hist2[tid] : 0u;
            unsigned incl = h;
#pragma unroll
            for (int off = 1; off < 64; off <<= 1) {
                unsigned v = (unsigned)__shfl_up((int)incl, off, 64);
                if (tid >= off) incl += v;
            }
            const unsigned less11 = s_less11;
            unsigned long long bal = __ballot(tid < 32 && (less11 + incl >= k));
            const int sb = __ffsll(bal) - 1;
            const unsigned cumx = less11 + (unsigned)__shfl((int)(incl - h), sb, 64);
            if (tid == 0) { s_P16 = (B11 << 5) | (unsigned)sb; s_j = k - cumx; }
        }
        __syncthreads();
        const unsigned P16 = s_P16;
        const unsigned j   = s_j;

        // ---- Phase D: gather boundary candidates (ballot-prefix alloc) ----
        // Slot order differs from serial-atomic version but Phase E re-ranks
        // by (bits,idx), so any slot assignment is equivalent.
        // bits16 can never be 0xFFFF (d >= 0 finite) -> safe marker.
#pragma unroll
        for (int x = 0; x < 16; ++x) {
            const unsigned bits = rbits[x];
            const bool pred = (bits >> 16) == P16;
            const unsigned long long pm = __ballot(pred);
            if (pred) {
                const int leader = __ffsll((long long)pm) - 1;
                unsigned base = 0;
                if (l == leader)
                    base = atomicAdd(&s_ncand, (unsigned)__popcll(pm));
                base = (unsigned)__shfl((int)base, leader, 64);
                const unsigned w = base
                    + (unsigned)__popcll(pm & ((1ull << l) - 1ull));
                if (w < CAP) {
                    cand_bits[w] = bits;
                    cand_idx[w]  = (unsigned short)((x >> 2) * 4096 + tid * 4
                                                    + (x & 3));
                    rbits[x] = 0xFFFF0000u | w;
                }
            }
        }
        __syncthreads();

        // ---- Phase E: rank candidates (tie -> lowest index) -> flags ------
        const unsigned cnum = min(s_ncand, (unsigned)CAP);
        for (unsigned t = tid; t < cnum; t += TPB) {
            const unsigned bt = cand_bits[t];
            const unsigned it = cand_idx[t];
            unsigned rank = 0;
            for (unsigned u = 0; u < cnum; ++u) {
                const unsigned bu = cand_bits[u];
                rank += (bu < bt) || (bu == bt && (unsigned)cand_idx[u] < it);
            }
            sel_flags[t] = (rank < j) ? (unsigned char)1 : (unsigned char)0;
        }
        __syncthreads();
    }

    // ---- Phase F: write both masks (registers + flags), float4 stores -----
    const unsigned P16f = (k > 0) ? s_P16 : 0u;
#pragma unroll
    for (int it = 0; it < 4; ++it) {
        const int i0 = it * 4096 + tid * 4;
        float4 o0, o1;
        float* o0p = &o0.x; float* o1p = &o1.x;
#pragma unroll
        for (int jj = 0; jj < 4; ++jj) {
            const unsigned v   = rbits[it * 4 + jj];
            const unsigned v16 = v >> 16;
            bool sel = false;
            if (k > 0) {
                sel = (v16 == 0xFFFFu) ? (sel_flags[v & (CAP - 1u)] != 0)
                                       : (v16 < P16f);
            }
            const float mvv = rmv[it * 4 + jj];
            o0p[jj] = sel ? 0.0f  : mvv;
            o1p[jj] = sel ? 32.0f : (1.0f - mvv);
        }
        *(float4*)(out0 + (size_t)b * N_ + i0) = o0;
        *(float4*)(out1 + (size_t)b * N_ + i0) = o1;
    }
}

extern "C" void kernel_launch(void* const* d_in, const int* in_sizes, int n_in,
                              void* d_out, int out_size, void* d_ws, size_t ws_size,
                              hipStream_t stream) {
    const float* pos   = (const float*)d_in[0];   // [B,N,3]
    const float* rmask = (const float*)d_in[1];   // [B,N]
    const float* apos  = (const float*)d_in[2];   // [B,A,3]
    const float* amask = (const float*)d_in[3];   // [B,A]
    // d_in[4] = max_p (unused by the reference outputs)
    const int*   topk  = (const int*)d_in[5];

    float* out0 = (float*)d_out;
    float* out1 = out0 + (size_t)B_ * N_;

    fused_kernel<<<B_, TPB, 0, stream>>>(pos, rmask, apos, amask, topk, out0, out1);
}

// Round 7
// 210.383 us; speedup vs baseline: 1.1696x; 1.1696x over previous
//
#include <hip/hip_runtime.h>

#pragma clang fp contract(off)

#define B_   512
#define N_   16384
#define A_   64
#define TPB  1024
#define CAP  2048
#define ITERS 4              // N_ / (TPB*4)

// One block per batch: centroid (bit-exact numpy order) + distances +
// exact top-k select (16-bit radix + boundary rank) + both mask writes.
// NOTE (rounds 1-6): this structure sits on an empirical per-CU wall of
// ~5.7 cycles/element that is invariant to pipeline depth (gl2lds staging,
// rounds 2-3), barrier discipline (round 3), store policy (round 4, nt),
// batch chaining (round 5), and atomic aggregation (round 6). All captured
// counters <40% utilized at this point; do not re-try those axes.
__global__ __launch_bounds__(TPB) void fused_kernel(
    const float* __restrict__ pos,   const float* __restrict__ mask,
    const float* __restrict__ apos,  const float* __restrict__ amask,
    const int*   __restrict__ topk_ptr,
    float* __restrict__ out0, float* __restrict__ out1)
{
#pragma clang fp contract(off)
    __shared__ unsigned short dist16[N_];     // 32 KB: top-16 bits of dist
    __shared__ unsigned       hist[2048];     // 8 KB: 11-bit prefix histogram
    __shared__ unsigned       hist2[32];      // 5-bit refinement
    __shared__ unsigned       cand_bits[CAP]; // boundary candidates
    __shared__ unsigned short cand_idx[CAP];
    __shared__ float          s_atoms[A_ * 3 + A_];  // 192 pos + 64 mask
    __shared__ float          s_c[3];
    __shared__ unsigned       s_B11, s_less11, s_P16, s_j, s_ncand, s_k;

    const int tid = threadIdx.x;
    const int b   = blockIdx.x;
    const float* __restrict__ p = pos  + (size_t)b * N_ * 3;
    const float* __restrict__ m = mask + (size_t)b * N_;

    // ---- init: zero hists, stage atoms coalesced, load k ------------------
    hist[tid]        = 0u;
    hist[tid + 1024] = 0u;
    if (tid < 32) hist2[tid] = 0u;
    if (tid < 256)
        s_atoms[tid] = (tid < 192) ? apos[(size_t)b * 192 + tid]
                                   : amask[(size_t)b * 64 + (tid - 192)];
    if (tid == 0) {
        s_ncand = 0u;
        int kk = *topk_ptr;
        if (kk < 0)  kk = 0;
        if (kk > N_) kk = N_;
        s_k = (unsigned)kk;
    }
    __syncthreads();

    // ---- centroid: lanes 0..2 = component sums (numpy sequential axis=-2),
    //      lane 3 = mask pairwise-8 sum (numpy pairwise for n=64) ----------
    if (tid < 64) {
        float comp = 0.0f, ms = 0.0f;
        if (tid < 3) {
            comp = s_atoms[tid];
            for (int a = 1; a < A_; ++a) comp += s_atoms[a * 3 + tid];
        }
        if (tid == 3) {
            const float* am = s_atoms + 192;
            float r0 = am[0], r1 = am[1], r2 = am[2], r3 = am[3];
            float r4 = am[4], r5 = am[5], r6 = am[6], r7 = am[7];
            for (int i = 8; i < A_; i += 8) {
                r0 += am[i + 0]; r1 += am[i + 1]; r2 += am[i + 2]; r3 += am[i + 3];
                r4 += am[i + 4]; r5 += am[i + 5]; r6 += am[i + 6]; r7 += am[i + 7];
            }
            ms = ((r0 + r1) + (r2 + r3)) + ((r4 + r5) + (r6 + r7));
        }
        ms = __shfl(ms, 3, 64);
        if (tid < 3) s_c[tid] = comp / ms;   // correctly-rounded fp32 divide
    }
    __syncthreads();

    const float cx = s_c[0], cy = s_c[1], cz = s_c[2];
    const unsigned k = s_k;

    // ---- Phase A: distances (bit-exact), keep bits+mask in registers ------
    unsigned rbits[ITERS * 4];
    float    rm[ITERS * 4];
#pragma unroll
    for (int it = 0; it < ITERS; ++it) {
        const int i0 = it * (TPB * 4) + tid * 4;
        const float4 pa = *(const float4*)(p + (size_t)i0 * 3);
        const float4 pb = *(const float4*)(p + (size_t)i0 * 3 + 4);
        const float4 pc = *(const float4*)(p + (size_t)i0 * 3 + 8);
        const float4 mv = *(const float4*)(m + i0);
        const float px[4] = {pa.x, pa.w, pb.z, pc.y};
        const float py[4] = {pa.y, pb.x, pb.w, pc.z};
        const float pz[4] = {pa.z, pb.y, pc.x, pc.w};
        const float mm[4] = {mv.x, mv.y, mv.z, mv.w};
        unsigned short loc[4];
#pragma unroll
        for (int j = 0; j < 4; ++j) {
            float dx = cx - px[j], dy = cy - py[j], dz = cz - pz[j];
            float dx2 = dx * dx, dy2 = dy * dy, dz2 = dz * dz;
            float s = (dx2 + dy2) + dz2;     // numpy sum order (no FMA)
            s = s + 1e-12f;
            float d = sqrtf(s);              // correctly rounded
            float im = (1.0f - mm[j]) * 1e10f;
            d = d + im;
            const unsigned bits = __float_as_uint(d);  // monotone, d >= 0
            rbits[it * 4 + j] = bits;
            rm[it * 4 + j]    = mm[j];
            loc[j] = (unsigned short)(bits >> 16);
            atomicAdd(&hist[bits >> 21], 1u);
        }
        *(ushort4*)&dist16[i0] = make_ushort4(loc[0], loc[1], loc[2], loc[3]);
    }
    __syncthreads();

    if (k > 0) {
        // ---- Phase B: wave-0 shuffle scan finds the 11-bit bucket ---------
        if (tid < 64) {
            unsigned s = 0;
#pragma unroll
            for (int i = 0; i < 32; ++i) s += hist[tid * 32 + i];
            unsigned incl = s;
#pragma unroll
            for (int off = 1; off < 64; off <<= 1) {
                unsigned v = (unsigned)__shfl_up((int)incl, off, 64);
                if (tid >= off) incl += v;
            }
            unsigned long long bal = __ballot(incl >= k);
            const int g = __ffsll(bal) - 1;
            const unsigned cum1 = (unsigned)__shfl((int)(incl - s), g, 64);

            unsigned h2 = (tid < 32) ? hist[g * 32 + tid] : 0u;
            unsigned incl2 = h2;
#pragma unroll
            for (int off = 1; off < 64; off <<= 1) {
                unsigned v = (unsigned)__shfl_up((int)incl2, off, 64);
                if (tid >= off) incl2 += v;
            }
            unsigned long long bal2 = __ballot(tid < 32 && (cum1 + incl2 >= k));
            const int sb = __ffsll(bal2) - 1;
            const unsigned cum2 = cum1 + (unsigned)__shfl((int)(incl2 - h2), sb, 64);
            if (tid == 0) { s_B11 = (unsigned)(g * 32 + sb); s_less11 = cum2; }
        }
        __syncthreads();
        const unsigned B11 = s_B11;

        // ---- Phase C: refine low-5 bits (from registers, no re-read) ------
#pragma unroll
        for (int x = 0; x < ITERS * 4; ++x) {
            const unsigned v = rbits[x] >> 16;
            if ((v >> 5) == B11) atomicAdd(&hist2[v & 31u], 1u);
        }
        __syncthreads();
        if (tid < 64) {
            unsigned h = (tid < 32) ? hist2[tid] : 0u;
            unsigned incl = h;
#pragma unroll
            for (int off = 1; off < 64; off <<= 1) {
                unsigned v = (unsigned)__shfl_up((int)incl, off, 64);
                if (tid >= off) incl += v;
            }
            const unsigned less11 = s_less11;
            unsigned long long bal = __ballot(tid < 32 && (less11 + incl >= k));
            const int sb = __ffsll(bal) - 1;
            const unsigned cumx = less11 + (unsigned)__shfl((int)(incl - h), sb, 64);
            if (tid == 0) { s_P16 = (B11 << 5) | (unsigned)sb; s_j = k - cumx; }
        }
        __syncthreads();
        const unsigned P16 = s_P16;
        const unsigned j   = s_j;

        // ---- Phase D: gather boundary candidates from registers -----------
#pragma unroll
        for (int it = 0; it < ITERS; ++it) {
#pragma unroll
            for (int jj = 0; jj < 4; ++jj) {
                const unsigned bits = rbits[it * 4 + jj];
                if ((bits >> 16) == P16) {
                    const unsigned w = atomicAdd(&s_ncand, 1u);
                    if (w < CAP) {
                        cand_bits[w] = bits;
                        cand_idx[w]  = (unsigned short)(it * (TPB * 4) + tid * 4 + jj);
                    }
                }
            }
        }
        __syncthreads();

        // ---- Phase E: rank candidates (tie -> lowest index), mark ---------
        const unsigned c = min(s_ncand, (unsigned)CAP);
        for (unsigned t = tid; t < c; t += TPB) {
            const unsigned bt = cand_bits[t];
            const unsigned it = cand_idx[t];
            unsigned rank = 0;
            for (unsigned u = 0; u < c; ++u) {
                const unsigned bu = cand_bits[u];
                rank += (bu < bt) || (bu == bt && (unsigned)cand_idx[u] < it);
            }
            if (rank < j) dist16[it] = 0;   // 0 < P16 always (d >= 1e-6)
        }
        __syncthreads();
    }

    // ---- Phase F: write both masks (mask values from registers) -----------
    const unsigned P16f = (k > 0) ? s_P16 : 0u;
#pragma unroll
    for (int it = 0; it < ITERS; ++it) {
        const int i0 = it * (TPB * 4) + tid * 4;
        const ushort4 dv = *(const ushort4*)&dist16[i0];
        const unsigned short dvs[4] = {dv.x, dv.y, dv.z, dv.w};
        float4 o0, o1;
        float* o0p = &o0.x; float* o1p = &o1.x;
#pragma unroll
        for (int jj = 0; jj < 4; ++jj) {
            const bool sel = (unsigned)dvs[jj] < P16f;
            const float mv = rm[it * 4 + jj];
            o0p[jj] = sel ? 0.0f  : mv;
            o1p[jj] = sel ? 32.0f : (1.0f - mv);
        }
        *(float4*)(out0 + (size_t)b * N_ + i0) = o0;
        *(float4*)(out1 + (size_t)b * N_ + i0) = o1;
    }
}

extern "C" void kernel_launch(void* const* d_in, const int* in_sizes, int n_in,
                              void* d_out, int out_size, void* d_ws, size_t ws_size,
                              hipStream_t stream) {
    const float* pos   = (const float*)d_in[0];   // [B,N,3]
    const float* rmask = (const float*)d_in[1];   // [B,N]
    const float* apos  = (const float*)d_in[2];   // [B,A,3]
    const float* amask = (const float*)d_in[3];   // [B,A]
    // d_in[4] = max_p (unused by the reference outputs)
    const int*   topk  = (const int*)d_in[5];

    float* out0 = (float*)d_out;
    float* out1 = out0 + (size_t)B_ * N_;

    fused_kernel<<<B_, TPB, 0, stream>>>(pos, rmask, apos, amask, topk, out0, out1);
}